// Round 11
// baseline (260.473 us; speedup 1.0000x reference)
//
#include <hip/hip_runtime.h>
#include <math.h>

// Problem constants
#define T_SEQ 2048
#define D_MODEL 2048
#define H_HEADS 16
#define DH 128
#define DR 64
#define DC 64
#define D_LAT 512
// Attention segmentation (64-key rounds): q-tile qt needs nchunk = 2qt+2
// rounds; split into ceil(nchunk/SEGLEN) contiguous segments, <=7 rounds each.
// Sum over qt of nseg = 46 segments/head, 736 blocks total.
#define SEGLEN 7
#define NSEG_TOT 46
#define NSEG_OF(q) ((2 * (q) + 2 + SEGLEN - 1) / SEGLEN)
// SCALE_ATTN * log2(e): Q pre-scaled by this; softmax uses exp2 (fixed max = 0;
// scores are distribution-bounded |s| < ~2, no overflow possible)
#define QSCALE (0.08838834764831845f * 1.4426950408889634f)

typedef __attribute__((ext_vector_type(8))) short short8;
typedef __attribute__((ext_vector_type(4))) short short4v;
typedef __attribute__((ext_vector_type(4))) float f32x4;

#if __has_builtin(__builtin_amdgcn_exp2f)
#define EXP2(x) __builtin_amdgcn_exp2f(x)
#else
#define EXP2(x) exp2f(x)
#endif

__device__ __forceinline__ float bf2f(short b) {
    unsigned u = ((unsigned)(unsigned short)b) << 16;
    return __builtin_bit_cast(float, u);
}
__device__ __forceinline__ short f2bf(float f) {
    unsigned u = __builtin_bit_cast(unsigned, f);
    unsigned r = u + 0x7fffu + ((u >> 16) & 1u);   // RNE
    return (short)(r >> 16);
}
__device__ __forceinline__ unsigned f2bf_tru(float f) {
    return __builtin_bit_cast(unsigned, f) >> 16;   // truncated bf16 bits
}

#define GLD_LDS(gp, lp) \
    __builtin_amdgcn_global_load_lds( \
        (const __attribute__((address_space(1))) void*)(gp), \
        (__attribute__((address_space(3))) void*)(lp), 16, 0, 0)

// ---------------------------------------------------------------------------
// Merged prep: cast x -> bf16 (blocks 0..4095) + 8 weight cast-transposes.
// ---------------------------------------------------------------------------
__device__ __forceinline__ void ct_tile(float (*tile)[33],
                                        const float* __restrict__ W,
                                        short* __restrict__ Wt,
                                        int R, int C, int ldo, int rel) {
    int bx = rel % (C / 32), by = rel / (C / 32);
    int c0 = bx * 32, r0 = by * 32;
    int tx = threadIdx.x & 31, ty = threadIdx.x >> 5;  // ty 0..7
    #pragma unroll
    for (int i = 0; i < 4; ++i)
        tile[ty + i * 8][tx] = W[(size_t)(r0 + ty + i * 8) * C + c0 + tx];
    __syncthreads();
    #pragma unroll
    for (int i = 0; i < 4; ++i)
        Wt[(size_t)(c0 + ty + i * 8) * ldo + r0 + tx] = f2bf(tile[tx][ty + i * 8]);
    __syncthreads();
}

__global__ __launch_bounds__(256) void prep(const float* __restrict__ x,
                                            short* __restrict__ xb,
                                            const float* __restrict__ Wqd,
                                            const float* __restrict__ Wkvd,
                                            const float* __restrict__ Wqr,
                                            const float* __restrict__ Wkr,
                                            const float* __restrict__ Wqu,
                                            const float* __restrict__ Wku,
                                            const float* __restrict__ Wvu,
                                            const float* __restrict__ Wo,
                                            short* __restrict__ WdT,
                                            short* __restrict__ WupT2,
                                            short* __restrict__ WoT) {
    __shared__ float tile[32][33];
    int bid = blockIdx.x;
    if (bid < 4096) {
        int i = bid * 1024 + threadIdx.x * 4;
        float4 f = *(const float4*)&x[i];
        short4v o;
        o.x = f2bf(f.x); o.y = f2bf(f.y); o.z = f2bf(f.z); o.w = f2bf(f.w);
        *(short4v*)&xb[i] = o;
    } else if (bid < 5120) {
        ct_tile(tile, Wqd,  WdT + (size_t)0 * 2048,    2048, 512,  2048, bid - 4096);
    } else if (bid < 6144) {
        ct_tile(tile, Wkvd, WdT + (size_t)512 * 2048,  2048, 512,  2048, bid - 5120);
    } else if (bid < 8192) {
        ct_tile(tile, Wqr,  WdT + (size_t)1024 * 2048, 2048, 1024, 2048, bid - 6144);
    } else if (bid < 10240) {
        ct_tile(tile, Wkr,  WdT + (size_t)2048 * 2048, 2048, 1024, 2048, bid - 8192);
    } else if (bid < 10752) {
        ct_tile(tile, Wqu,  WupT2 + (size_t)0 * 512,    512, 1024, 512, bid - 10240);
    } else if (bid < 11264) {
        ct_tile(tile, Wku,  WupT2 + (size_t)1024 * 512, 512, 1024, 512, bid - 10752);
    } else if (bid < 12288) {
        ct_tile(tile, Wvu,  WupT2 + (size_t)2048 * 512, 512, 2048, 512, bid - 11264);
    } else {
        ct_tile(tile, Wo,   WoT, 2048, 2048, 2048, bid - 12288);
    }
}

// ---------------------------------------------------------------------------
// v transpose -> chunk-blocked vTc[h*64 + chunk][d128][32 keys], 8KB panels.
// In-row key order bakes the attn read swizzle AND the swapped-QK in-register
// P key order: physical group gpos of row d stores logical group
// g = gpos^(d&3); within the group, short j' holds chunk-local key
//   4g + (j'&3) + 16*(j'>>2)
// so attn's vf read (group quad^(d&3), 8 shorts) yields true keys matching
// the swapped-QK P fragment (key = 4*quad + r + 16*n at slot j' = 4n+r).
// Int slot mi (2 shorts) therefore packs keys (lo, lo+1) with
//   lo = 4g + 2*(mi&1) + 16*(mi>>1).
// V staging stays fully contiguous 1KB global_load_lds.
// ---------------------------------------------------------------------------
__global__ __launch_bounds__(256) void transpose_bf16(const short* __restrict__ in,
                                                      short* __restrict__ vTc,
                                                      int ldi) {
    __shared__ short tile[64][65];
    int c0 = blockIdx.x * 64, t0 = blockIdx.y * 64;   // c0: d-index, t0: keys
    int tx = threadIdx.x & 31, ty = threadIdx.x >> 5;  // ty 0..7
    #pragma unroll
    for (int i = 0; i < 8; ++i) {
        int r = ty + i * 8;
        int vv = *(const int*)&in[(size_t)(t0 + r) * ldi + c0 + tx * 2];
        tile[r][tx * 2]     = (short)(vv & 0xffff);
        tile[r][tx * 2 + 1] = (short)(((unsigned)vv) >> 16);
    }
    __syncthreads();
    // write 2048 ints (64 keys x 64 d) = 8 per thread, coalesced in vTc
    #pragma unroll
    for (int i = 0; i < 8; ++i) {
        int G = i * 256 + threadIdx.x;     // 0..2047
        int ch2 = G >> 10;                 // which 32-key chunk of this tile
        int rem = G & 1023;
        int dl = rem >> 4;                 // local d 0..63
        int mp = rem & 15;                 // int slot within 32-key row
        int dval = c0 + dl;
        int h = dval >> 7, d128 = dval & 127;
        int g  = (mp >> 2) ^ (d128 & 3);   // logical key group
        int mi = mp & 3;
        int kl = 4 * g + 2 * (mi & 1) + 16 * (mi >> 1);   // lo key (local)
        unsigned lo = (unsigned short)tile[ch2 * 32 + kl][dl];
        unsigned hi = (unsigned short)tile[ch2 * 32 + kl + 1][dl];
        int chg = (t0 >> 5) + ch2;         // global 32-key chunk
        size_t off = ((size_t)(h * 64 + chg)) * 4096 + d128 * 32 + mp * 2;
        *(int*)&vTc[off] = (int)(lo | (hi << 16));
    }
}

// ---------------------------------------------------------------------------
// MFMA bf16 GEMM, 1D grid with XCD super-tile swizzle. BK=64 rounds
// (skeleton amortization) with source-XOR staging + read-XOR (rule-21):
// global col-group cg^(row&7) lands in linear LDS; frag reads use
// (kk*4+quad)^(lr&7) — uniform 8 dwords/bank, conflict-free. LDS 32KB.
// K-split via decoded bz; C = Asel @ Bt^T; epilogue scale cols < scut.
// (r10 lesson / rule #19: keep this kernel free of extra epilogue paths —
// the fused-V variant raised VGPR 76->88 for ALL call sites, +8us on the
// down-GEMM alone.)
// ---------------------------------------------------------------------------
__global__ __launch_bounds__(256) void gemm_bt(const short* __restrict__ A,
                                               const short* __restrict__ A2,
                                               const short* __restrict__ Bt,
                                               short* __restrict__ C0,
                                               short* __restrict__ C1,
                                               short* __restrict__ C2,
                                               short* __restrict__ C3,
                                               int N, int Kblk,
                                               int lda, int ldb, int ldc,
                                               int ncut, int scut, float cscale) {
    __shared__ short As[128 * 64];
    __shared__ short Bs[128 * 64];
    const int tid = threadIdx.x;
    const int wave = tid >> 6, lane = tid & 63;
    // XCD decode: lin%8 = XCD (dispatch heuristic). 4 N-bands x 2 M-bands.
    const int lin = blockIdx.x;
    const int X = N >> 7, Xq = X >> 2;
    const int xcd = lin & 7;
    int r = lin >> 3;
    const int bx = (xcd & 3) * Xq + (r % Xq); r /= Xq;
    const int by = (xcd >> 2) * 8 + (r & 7);
    const int bz = r >> 3;
    const int row0 = by * 128, col0 = bx * 128;
    const int kbase = bz * Kblk;
    const short* Ause = (col0 < ncut) ? A : A2;
    short* Cuse = (bz == 0) ? C0 : (bz == 1) ? C1 : (bz == 2) ? C2 : C3;
    const int wr = (wave >> 1) * 64, wc = (wave & 1) * 64;
    const int lr = lane & 15, quad = lane >> 4;

    f32x4 acc[4][4];
    #pragma unroll
    for (int i = 0; i < 4; ++i)
        #pragma unroll
        for (int j = 0; j < 4; ++j) acc[i][j] = (f32x4){0.f, 0.f, 0.f, 0.f};

    for (int k0 = kbase; k0 < kbase + Kblk; k0 += 64) {
        __syncthreads();
        // stage 128x64 A and B panels: idx 0..1023, row=idx>>3, cg=idx&7,
        // source col-group swizzled by row&7, LDS linear (gld_lds order)
        #pragma unroll
        for (int it = 0; it < 4; ++it) {
            int idx = wave * 64 + it * 256 + lane;      // 0..1023
            int row = idx >> 3;
            int scg = (idx & 7) ^ (row & 7);
            const short* ga = Ause + (size_t)(row0 + row) * lda + k0 + scg * 8;
            const short* gb = Bt   + (size_t)(col0 + row) * ldb + k0 + scg * 8;
            int lds0 = (wave * 64 + it * 256) * 8;
            GLD_LDS(ga, &As[lds0]);
            GLD_LDS(gb, &Bs[lds0]);
        }
        __syncthreads();

        #pragma unroll
        for (int kk = 0; kk < 2; ++kk) {
            short8 af[4], bfr[4];
            #pragma unroll
            for (int i = 0; i < 4; ++i)
                af[i] = *(const short8*)
                    &As[(wr + i * 16 + lr) * 64 + (((kk * 4 + quad) ^ (lr & 7)) * 8)];
            #pragma unroll
            for (int j = 0; j < 4; ++j)
                bfr[j] = *(const short8*)
                    &Bs[(wc + j * 16 + lr) * 64 + (((kk * 4 + quad) ^ (lr & 7)) * 8)];
            #pragma unroll
            for (int i = 0; i < 4; ++i)
                #pragma unroll
                for (int j = 0; j < 4; ++j)
                    acc[i][j] = __builtin_amdgcn_mfma_f32_16x16x32_bf16(
                        af[i], bfr[j], acc[i][j], 0, 0, 0);
        }
    }

    const float sc = (col0 < scut) ? cscale : 1.0f;
    #pragma unroll
    for (int i = 0; i < 4; ++i) {
        int rb = row0 + wr + i * 16 + quad * 4;
        #pragma unroll
        for (int j = 0; j < 4; ++j) {
            int c = col0 + wc + j * 16 + lr;
            #pragma unroll
            for (int rr = 0; rr < 4; ++rr)
                Cuse[(size_t)(rb + rr) * ldc + c] = f2bf(acc[i][j][rr] * sc);
        }
    }
}

// ---------------------------------------------------------------------------
// finish_down: cat += pdown (everywhere) then RoPE on cols 1024..3071.
// Pair-aware: thread owns 8 cols in a low 32-half AND the matching +32 cols.
// Grid 2048 (one row), 192 threads x 16 elems = 3072 cols.
// qr (cols 1024..2047) additionally scaled by QSCALE.
// ---------------------------------------------------------------------------
__global__ __launch_bounds__(192) void finish_down(short* __restrict__ cat,
                                                   const short* __restrict__ pdown) {
    const int t = blockIdx.x;
    const int k8 = threadIdx.x * 8;                     // 0..1528
    const int c0 = ((k8 >> 5) << 6) + (k8 & 31);        // low-half col
    const size_t lo = (size_t)t * 3072 + c0;
    const size_t hi = lo + 32;
    short8 al = *(const short8*)&cat[lo];
    short8 ah = *(const short8*)&cat[hi];
    short8 bl = *(const short8*)&pdown[lo];
    short8 bh = *(const short8*)&pdown[hi];
    float xl[8], xh[8];
    #pragma unroll
    for (int j = 0; j < 8; ++j) {
        xl[j] = bf2f(al[j]) + bf2f(bl[j]);
        xh[j] = bf2f(ah[j]) + bf2f(bh[j]);
    }
    if (c0 >= 1024) {   // rope region
        float sc = (c0 < 2048) ? QSCALE : 1.0f;
        #pragma unroll
        for (int j = 0; j < 8; ++j) {
            int i = (c0 & 31) + j;
            float freq = (float)t * __powf(10000.0f, -(float)i / 32.0f);
            float cs = __cosf(freq), sn = __sinf(freq);
            float r1 = (xl[j] * cs - xh[j] * sn) * sc;
            float r2 = (xl[j] * sn + xh[j] * cs) * sc;
            xl[j] = r1; xh[j] = r2;
        }
    }
    short8 ol, oh;
    #pragma unroll
    for (int j = 0; j < 8; ++j) { ol[j] = f2bf(xl[j]); oh[j] = f2bf(xh[j]); }
    *(short8*)&cat[lo] = ol;
    *(short8*)&cat[hi] = oh;
}

// ---------------------------------------------------------------------------
// out = p0+p1 (bf16 partials -> fp32), 4 elems/thread
// ---------------------------------------------------------------------------
__global__ __launch_bounds__(256) void add_out_f32(const short* __restrict__ p0,
                                                   const short* __restrict__ p1,
                                                   float* __restrict__ out) {
    int i = (blockIdx.x * 256 + threadIdx.x) * 4;
    short4v a = *(const short4v*)&p0[i];
    short4v b = *(const short4v*)&p1[i];
    float4 o;
    o.x = bf2f(a.x) + bf2f(b.x);
    o.y = bf2f(a.y) + bf2f(b.y);
    o.z = bf2f(a.z) + bf2f(b.z);
    o.w = bf2f(a.w) + bf2f(b.w);
    *(float4*)&out[i] = o;
}

// ---------------------------------------------------------------------------
// Flash-decoding MFMA attention, 64-key rounds, 3-way balanced variable split.
// Swapped QK^T + in-register P (r9, verified): mfma(K, Q) puts
// S[key = s0+16n+4*quad+r][qrow = qrow0+lr] in sacc; after mask+exp2 this IS
// the PV A-fragment — no Ps LDS round-trip. V key order baked into vTc.
// LDS 32KB. THIS ROUND (+T5): s_setprio(1) wraps both MFMA clusters —
// 2-3 co-resident blocks at independent phases give the CU scheduler a
// role split to arbitrate (m191: attn +4-7%; sync structure untouched).
// ---------------------------------------------------------------------------
__global__ __launch_bounds__(256) void attn_mla_split(const short* __restrict__ qkup,
                                                      const short* __restrict__ cat,
                                                      const short* __restrict__ vTc,
                                                      short* __restrict__ slabA,
                                                      short* __restrict__ slabB,
                                                      float* __restrict__ lpart) {
    const int lin = blockIdx.x;        // 0..735
    const int xcd = lin & 7;
    int k_ = lin >> 3;                 // 0..91
    const int h = xcd + 8 * (k_ & 1);
    const int pp = k_ >> 1;            // 0..45: per-head segment index
    // decode pp -> (qt, s): nseg(q) = ceil((2q+2)/SEGLEN)
    int qt = 0, s = 0, acc = 0;
    #pragma unroll
    for (int q = 0; q < 16; ++q) {
        const int ns = NSEG_OF(q);
        if (pp >= acc) { qt = q; s = pp - acc; }
        acc += ns;
    }
    const int nchunk = 2 * qt + 2;             // 64-key rounds for this tile
    const int nsq = NSEG_OF(qt);
    const int cbase = nchunk / nsq, crem = nchunk % nsq;
    const int c0 = s * cbase + (s < crem ? s : crem);
    const int c1 = c0 + cbase + (s < crem ? 1 : 0);

    const int tid = threadIdx.x;
    const int wave = tid >> 6, lane = tid & 63;
    const int lr = lane & 15, quad = lane >> 4;

    __shared__ short Ks[2][32 * 128];    // two 32-key panels
    __shared__ short Vst[2][128 * 32];

    const short8 ones = {0x3F80, 0x3F80, 0x3F80, 0x3F80,
                         0x3F80, 0x3F80, 0x3F80, 0x3F80};  // bf16 1.0 x8

    const int Q0 = qt * 128;
    const int qrowA = Q0 + wave * 16;   // sub-tile A rows
    const int qrowB = qrowA + 64;       // sub-tile B rows

    // Q fragments for both sub-tiles: k-chunks 0,1 content (qkup, pre-scaled);
    // 2,3 rope (cat cols 1024..2047, pre-scaled in finish_down)
    short8 qf[2][4];
    #pragma unroll
    for (int sb = 0; sb < 2; ++sb) {
        int t = (sb ? qrowB : qrowA) + lr;
        #pragma unroll
        for (int kci = 0; kci < 4; ++kci) {
            const short* src = (kci < 2)
                ? qkup + (size_t)t * 4096 + h * 64
                : cat + (size_t)t * 3072 + 1024 + h * 64;
            qf[sb][kci] = *(const short8*)&src[(kci & 1) * 32 + quad * 8];
        }
    }

    // Hoisted staging pointers. K: loop-invariant swizzle (key+16/32/48 keeps
    // key&15 -> cg invariant). V: fully linear from chunk-blocked vTc.
    const int idx = wave * 64 + lane;
    const int key = idx >> 4;
    const int cg = (idx & 15) ^ (key & 15);
    const short* kp0 = (cg < 8)
        ? qkup + (size_t)key * 4096 + 1024 + h * 64 + cg * 8
        : cat + (size_t)key * 3072 + 2048 + h * 64 + (cg - 8) * 8;
    const int kst = (cg < 8) ? 4096 : 3072;      // shorts per key-row
    const short* kp1 = kp0 + (size_t)16 * kst;
    const short* vp0 = vTc + ((size_t)h * 64 + (size_t)c0 * 2) * 4096 + idx * 8;
    kp0 += (size_t)c0 * 64 * kst; kp1 += (size_t)c0 * 64 * kst;
    const int kadv = 64 * kst;                   // shorts per 64-key round
    const int kph = 32 * kst;                    // panel-1 key offset
    const int ldsA = (wave * 64) * 8;            // wave-uniform LDS bases
    const int ldsB = (wave * 64 + 256) * 8;

    f32x4 Oacc[2][8];
    #pragma unroll
    for (int sb = 0; sb < 2; ++sb)
        #pragma unroll
        for (int d = 0; d < 8; ++d) Oacc[sb][d] = (f32x4){0.f, 0.f, 0.f, 0.f};
    f32x4 Lacc[2];
    Lacc[0] = (f32x4){0.f, 0.f, 0.f, 0.f};
    Lacc[1] = (f32x4){0.f, 0.f, 0.f, 0.f};

    for (int cc = c0; cc < c1; ++cc) {
        __syncthreads();
        GLD_LDS(kp0,        &Ks[0][ldsA]);
        GLD_LDS(kp1,        &Ks[0][ldsB]);
        GLD_LDS(kp0 + kph,  &Ks[1][ldsA]);
        GLD_LDS(kp1 + kph,  &Ks[1][ldsB]);
        GLD_LDS(vp0,        &Vst[0][ldsA]);
        GLD_LDS(vp0 + 2048, &Vst[0][ldsB]);
        GLD_LDS(vp0 + 4096, &Vst[1][ldsA]);
        GLD_LDS(vp0 + 6144, &Vst[1][ldsB]);
        kp0 += kadv; kp1 += kadv; vp0 += 8192;
        __syncthreads();

        #pragma unroll
        for (int half = 0; half < 2; ++half) {
            const int s0 = cc * 64 + half * 32;
            if (s0 > qrowB + 15) continue;   // above diagonal (per-wave ok:
                                             // no barrier inside this body)
            const bool actA = (s0 <= qrowA + 15);
            const short* Kc = Ks[half];
            const short* Vc = Vst[half];

            // S^T = K Q^T (swapped): sacc[sb][n] reg r at lane (lr,quad) =
            //   S[key = s0+16n+4*quad+r][qrow = (sb?qrowB:qrowA)+lr]
            f32x4 sacc[2][2];
            #pragma unroll
            for (int sb = 0; sb < 2; ++sb)
                #pragma unroll
                for (int n = 0; n < 2; ++n) sacc[sb][n] = (f32x4){0.f, 0.f, 0.f, 0.f};
            __builtin_amdgcn_s_setprio(1);
            #pragma unroll
            for (int n = 0; n < 2; ++n) {
                #pragma unroll
                for (int kci = 0; kci < 4; ++kci) {
                    short8 kf = *(const short8*)
                        &Kc[(n * 16 + lr) * 128 + ((kci * 4 + quad) ^ lr) * 8];
                    if (actA)
                        sacc[0][n] = __builtin_amdgcn_mfma_f32_16x16x32_bf16(
                            kf, qf[0][kci], sacc[0][n], 0, 0, 0);
                    sacc[1][n] = __builtin_amdgcn_mfma_f32_16x16x32_bf16(
                        kf, qf[1][kci], sacc[1][n], 0, 0, 0);
                }
            }
            __builtin_amdgcn_s_setprio(0);
            // mask (diagonal chunks only) + exp2 -> in-register P fragment.
            // pa[sb] slot j' = 4n+r holds key s0+16n+4*quad+r for qrow0+lr.
            short8 paA, paB;
            #pragma unroll
            for (int sb = 0; sb < 2; ++sb) {
                if (sb == 0 && !actA) continue;
                const int qrow0 = sb ? qrowB : qrowA;
                if (s0 + 31 > qrow0) {
                    #pragma unroll
                    for (int n = 0; n < 2; ++n) {
                        #pragma unroll
                        for (int r = 0; r < 4; ++r) {
                            int kidx = s0 + n * 16 + quad * 4 + r;
                            sacc[sb][n][r] = (kidx <= qrow0 + lr)
                                           ? sacc[sb][n][r] : -1e30f;
                        }
                    }
                }
                int4 pw;
                pw.x = (int)(f2bf_tru(EXP2(sacc[sb][0][0])) |
                             (f2bf_tru(EXP2(sacc[sb][0][1])) << 16));
                pw.y = (int)(f2bf_tru(EXP2(sacc[sb][0][2])) |
                             (f2bf_tru(EXP2(sacc[sb][0][3])) << 16));
                pw.z = (int)(f2bf_tru(EXP2(sacc[sb][1][0])) |
                             (f2bf_tru(EXP2(sacc[sb][1][1])) << 16));
                pw.w = (int)(f2bf_tru(EXP2(sacc[sb][1][2])) |
                             (f2bf_tru(EXP2(sacc[sb][1][3])) << 16));
                if (sb) paB = __builtin_bit_cast(short8, pw);
                else    paA = __builtin_bit_cast(short8, pw);
            }
            // L + PV directly from registers (no Ps LDS round trip).
            __builtin_amdgcn_s_setprio(1);
            if (actA)
                Lacc[0] = __builtin_amdgcn_mfma_f32_16x16x32_bf16(paA, ones,
                                                                  Lacc[0], 0, 0, 0);
            Lacc[1] = __builtin_amdgcn_mfma_f32_16x16x32_bf16(paB, ones,
                                                              Lacc[1], 0, 0, 0);
            #pragma unroll
            for (int dt = 0; dt < 8; ++dt) {
                short8 vf = *(const short8*)
                    &Vc[(dt * 16 + lr) * 32 + (quad ^ (lr & 3)) * 8];
                if (actA)
                    Oacc[0][dt] = __builtin_amdgcn_mfma_f32_16x16x32_bf16(
                        paA, vf, Oacc[0][dt], 0, 0, 0);
                Oacc[1][dt] = __builtin_amdgcn_mfma_f32_16x16x32_bf16(
                    paB, vf, Oacc[1][dt], 0, 0, 0);
            }
            __builtin_amdgcn_s_setprio(0);
        }
    }

    // epilogue: unnormalized partial O tile (128x128 compact) + per-row l.
    const int slot = h * NSEG_TOT + pp;
    short* slotp = (slot < 512) ? slabA + (size_t)slot * 16384
                                : slabB + (size_t)(slot - 512) * 16384;
    #pragma unroll
    for (int sb = 0; sb < 2; ++sb) {
        const int rbase = wave * 16 + sb * 64 + quad * 4;
        #pragma unroll
        for (int r = 0; r < 4; ++r) {
            #pragma unroll
            for (int dt = 0; dt < 8; ++dt)
                slotp[(rbase + r) * 128 + dt * 16 + lr] = f2bf(Oacc[sb][dt][r]);
        }
        if (lr == 0) {
            #pragma unroll
            for (int r = 0; r < 4; ++r)
                lpart[(size_t)slot * 128 + rbase + r] = Lacc[sb][r];
        }
    }
}

// ---------------------------------------------------------------------------
// Combine: O[t, h*128+d] = (sum_s P_s) / (sum_s l_s), nseg(qt) partials.
// Grid 2048 (t), 256 thr: h = tid>>4, 8 d-elems each.
// ---------------------------------------------------------------------------
__global__ __launch_bounds__(256) void attn_combine(const short* __restrict__ slabA,
                                                    const short* __restrict__ slabB,
                                                    const float* __restrict__ lpart,
                                                    short* __restrict__ ao) {
    const int t = blockIdx.x;
    const int qt = t >> 7, rl = t & 127;
    const int h = threadIdx.x >> 4;
    const int di = (threadIdx.x & 15) * 8;
    int pf = 0;
    #pragma unroll
    for (int q = 0; q < 16; ++q)
        if (q < qt) pf += NSEG_OF(q);
    const int ns = NSEG_OF(qt);
    float o[8] = {0.f, 0.f, 0.f, 0.f, 0.f, 0.f, 0.f, 0.f};
    float den = 0.f;
    for (int s = 0; s < ns; ++s) {
        const int slot = h * NSEG_TOT + pf + s;
        const short* sp = (slot < 512) ? slabA + (size_t)slot * 16384
                                       : slabB + (size_t)(slot - 512) * 16384;
        short8 v = *(const short8*)&sp[rl * 128 + di];
        #pragma unroll
        for (int j = 0; j < 8; ++j) o[j] += bf2f(v[j]);
        den += lpart[(size_t)slot * 128 + rl];
    }
    float inv = 1.0f / den;
    short8 ov;
    #pragma unroll
    for (int j = 0; j < 8; ++j) ov[j] = f2bf(o[j] * inv);
    *(short8*)&ao[(size_t)t * 2048 + h * 128 + di] = ov;
}

// ---------------------------------------------------------------------------
// Launch
// ---------------------------------------------------------------------------
extern "C" void kernel_launch(void* const* d_in, const int* in_sizes, int n_in,
                              void* d_out, int out_size, void* d_ws, size_t ws_size,
                              hipStream_t stream) {
    const float* x        = (const float*)d_in[0];
    const float* Wq_down  = (const float*)d_in[1];
    const float* Wq_up    = (const float*)d_in[2];
    const float* Wq_rope  = (const float*)d_in[3];
    const float* Wkv_down = (const float*)d_in[4];
    const float* Wk_up    = (const float*)d_in[5];
    const float* Wv_up    = (const float*)d_in[6];
    const float* Wk_rope  = (const float*)d_in[7];
    const float* Wo       = (const float*)d_in[8];
    float* out = (float*)d_out;

    // Workspace carve (shorts), ~68.6 MB. Aliases by liveness:
    //   pdown  <- upcat2 (down-GEMM partial; upcat2 written later)
    //   aob    <- cat    (cat's qlat/kvlat/qr dead after attention)
    //   attn partial slots: slabA <- WdT+WupT2 (512 slots of 32KB),
    //                       slabB <- xb (224 slots) — all dead during attn
    //   pw0,pw1 <- upcat2 (2 slabs), dead after combine
    short* p = (short*)d_ws;
    short* xb     = p; p += (size_t)2048 * 2048;   // 8MB
    short* WoT    = p; p += (size_t)2048 * 2048;   // 8MB
    short* cat    = p; p += (size_t)2048 * 3072;   // 12MB [qlat|kvlat|qr|kr]
    short* upcat2 = p; p += (size_t)2048 * 4096;   // 16MB [qc|kc|v]
    short* WdT    = p; p += (size_t)3072 * 2048;   // 12MB
    short* WupT2  = p; p += (size_t)4096 * 512;    // 4MB
    short* vTc    = p; p += (size_t)2048 * 2048;   // 8MB (chunk-blocked V)
    float* lpart  = (float*)p;                     // 736*128 floats (~377KB)
    short* pdown   = upcat2;
    short* aob     = cat;
    short* slabA   = WdT;          // WdT+WupT2 contiguous = 16MB = 512 slots
    short* slabB   = xb;           // 8MB = 256 slots (224 used)
    short* pw0     = upcat2;
    short* pw1     = upcat2 + (size_t)2048 * 2048;

    // prep: cast x + all weight transposes (one launch)
    prep<<<dim3(16384), 256, 0, stream>>>(x, xb, Wq_down, Wkv_down, Wq_rope,
                                          Wk_rope, Wq_up, Wk_up, Wv_up, Wo,
                                          WdT, WupT2, WoT);

    // down+rope projection, K split in 2: cat (z=0) + pdown (z=1)
    gemm_bt<<<dim3(24 * 16 * 2), 256, 0, stream>>>(xb, xb, WdT, cat, pdown,
                                                   nullptr, nullptr,
                                                   3072, 1024,
                                                   2048, 2048, 3072, 1 << 30, 0, 1.f);

    // fused: cat += pdown, then RoPE on qr/kr (qr scaled by QSCALE)
    finish_down<<<dim3(2048), 192, 0, stream>>>(cat, pdown);

    // merged up projection: upcat2 = [qlat|kvlat] @ [Wq_up|Wk_up|Wv_up]^T
    // qc columns (<1024) pre-scaled by QSCALE in the epilogue
    gemm_bt<<<dim3(32 * 16 * 1), 256, 0, stream>>>(cat, cat + 512, WupT2,
                                                   upcat2, nullptr, nullptr, nullptr,
                                                   4096, 512,
                                                   3072, 512, 4096, 1024, 1024, QSCALE);

    // v transpose: upcat2 cols 2048..4095 -> chunk-blocked vTc
    transpose_bf16<<<dim3(32, 32), 256, 0, stream>>>(upcat2 + 2048, vTc, 4096);

    // attention partials (64-key rounds, balanced variable split) + combine
    attn_mla_split<<<dim3(16 * NSEG_TOT), 256, 0, stream>>>(upcat2, cat, vTc,
                                                            slabA, slabB, lpart);
    attn_combine<<<dim3(2048), 256, 0, stream>>>(slabA, slabB, lpart, aob);

    // output projection, K split in 2 with bf16 partials, then fp32 add
    gemm_bt<<<dim3(16 * 16 * 2), 256, 0, stream>>>(aob, aob, WoT, pw0, pw1,
                                                   nullptr, nullptr,
                                                   2048, 1024,
                                                   2048, 2048, 2048, 1 << 30, 0, 1.f);
    add_out_f32<<<dim3(2048 * 2048 / 1024), 256, 0, stream>>>(pw0, pw1, out);
}

// Round 12
// 253.065 us; speedup vs baseline: 1.0293x; 1.0293x over previous
//
#include <hip/hip_runtime.h>
#include <math.h>

// Problem constants
#define T_SEQ 2048
#define D_MODEL 2048
#define H_HEADS 16
#define DH 128
#define DR 64
#define DC 64
#define D_LAT 512
// Attention segmentation (64-key rounds): q-tile qt needs nchunk = 2qt+2
// rounds; split into ceil(nchunk/SEGLEN) contiguous segments, <=7 rounds each.
// Sum over qt of nseg = 46 segments/head, 736 blocks total.
#define SEGLEN 7
#define NSEG_TOT 46
#define NSEG_OF(q) ((2 * (q) + 2 + SEGLEN - 1) / SEGLEN)
// SCALE_ATTN * log2(e): Q pre-scaled by this; softmax uses exp2 (fixed max = 0;
// scores are distribution-bounded |s| < ~2, no overflow possible)
#define QSCALE (0.08838834764831845f * 1.4426950408889634f)

typedef __attribute__((ext_vector_type(8))) short short8;
typedef __attribute__((ext_vector_type(4))) short short4v;
typedef __attribute__((ext_vector_type(4))) float f32x4;

#if __has_builtin(__builtin_amdgcn_exp2f)
#define EXP2(x) __builtin_amdgcn_exp2f(x)
#else
#define EXP2(x) exp2f(x)
#endif

__device__ __forceinline__ float bf2f(short b) {
    unsigned u = ((unsigned)(unsigned short)b) << 16;
    return __builtin_bit_cast(float, u);
}
__device__ __forceinline__ short f2bf(float f) {
    unsigned u = __builtin_bit_cast(unsigned, f);
    unsigned r = u + 0x7fffu + ((u >> 16) & 1u);   // RNE
    return (short)(r >> 16);
}
__device__ __forceinline__ unsigned f2bf_tru(float f) {
    return __builtin_bit_cast(unsigned, f) >> 16;   // truncated bf16 bits
}

#define GLD_LDS(gp, lp) \
    __builtin_amdgcn_global_load_lds( \
        (const __attribute__((address_space(1))) void*)(gp), \
        (__attribute__((address_space(3))) void*)(lp), 16, 0, 0)

// ---------------------------------------------------------------------------
// Merged prep: cast x -> bf16 (blocks 0..4095) + 8 weight cast-transposes.
// ---------------------------------------------------------------------------
__device__ __forceinline__ void ct_tile(float (*tile)[33],
                                        const float* __restrict__ W,
                                        short* __restrict__ Wt,
                                        int R, int C, int ldo, int rel) {
    int bx = rel % (C / 32), by = rel / (C / 32);
    int c0 = bx * 32, r0 = by * 32;
    int tx = threadIdx.x & 31, ty = threadIdx.x >> 5;  // ty 0..7
    #pragma unroll
    for (int i = 0; i < 4; ++i)
        tile[ty + i * 8][tx] = W[(size_t)(r0 + ty + i * 8) * C + c0 + tx];
    __syncthreads();
    #pragma unroll
    for (int i = 0; i < 4; ++i)
        Wt[(size_t)(c0 + ty + i * 8) * ldo + r0 + tx] = f2bf(tile[tx][ty + i * 8]);
    __syncthreads();
}

__global__ __launch_bounds__(256) void prep(const float* __restrict__ x,
                                            short* __restrict__ xb,
                                            const float* __restrict__ Wqd,
                                            const float* __restrict__ Wkvd,
                                            const float* __restrict__ Wqr,
                                            const float* __restrict__ Wkr,
                                            const float* __restrict__ Wqu,
                                            const float* __restrict__ Wku,
                                            const float* __restrict__ Wvu,
                                            const float* __restrict__ Wo,
                                            short* __restrict__ WdT,
                                            short* __restrict__ WupT2,
                                            short* __restrict__ WoT) {
    __shared__ float tile[32][33];
    int bid = blockIdx.x;
    if (bid < 4096) {
        int i = bid * 1024 + threadIdx.x * 4;
        float4 f = *(const float4*)&x[i];
        short4v o;
        o.x = f2bf(f.x); o.y = f2bf(f.y); o.z = f2bf(f.z); o.w = f2bf(f.w);
        *(short4v*)&xb[i] = o;
    } else if (bid < 5120) {
        ct_tile(tile, Wqd,  WdT + (size_t)0 * 2048,    2048, 512,  2048, bid - 4096);
    } else if (bid < 6144) {
        ct_tile(tile, Wkvd, WdT + (size_t)512 * 2048,  2048, 512,  2048, bid - 5120);
    } else if (bid < 8192) {
        ct_tile(tile, Wqr,  WdT + (size_t)1024 * 2048, 2048, 1024, 2048, bid - 6144);
    } else if (bid < 10240) {
        ct_tile(tile, Wkr,  WdT + (size_t)2048 * 2048, 2048, 1024, 2048, bid - 8192);
    } else if (bid < 10752) {
        ct_tile(tile, Wqu,  WupT2 + (size_t)0 * 512,    512, 1024, 512, bid - 10240);
    } else if (bid < 11264) {
        ct_tile(tile, Wku,  WupT2 + (size_t)1024 * 512, 512, 1024, 512, bid - 10752);
    } else if (bid < 12288) {
        ct_tile(tile, Wvu,  WupT2 + (size_t)2048 * 512, 512, 2048, 512, bid - 11264);
    } else {
        ct_tile(tile, Wo,   WoT, 2048, 2048, 2048, bid - 12288);
    }
}

// ---------------------------------------------------------------------------
// v transpose -> chunk-blocked vTc[h*64 + chunk][d128][32 keys], 8KB panels.
// In-row key order bakes the attn read swizzle AND the swapped-QK in-register
// P key order (verified on HW by r9's pass). Int slot mi packs keys (lo,lo+1),
// lo = 4g + 2*(mi&1) + 16*(mi>>1), with g = (mp>>2)^(d&3).
// ---------------------------------------------------------------------------
__global__ __launch_bounds__(256) void transpose_bf16(const short* __restrict__ in,
                                                      short* __restrict__ vTc,
                                                      int ldi) {
    __shared__ short tile[64][65];
    int c0 = blockIdx.x * 64, t0 = blockIdx.y * 64;   // c0: d-index, t0: keys
    int tx = threadIdx.x & 31, ty = threadIdx.x >> 5;  // ty 0..7
    #pragma unroll
    for (int i = 0; i < 8; ++i) {
        int r = ty + i * 8;
        int vv = *(const int*)&in[(size_t)(t0 + r) * ldi + c0 + tx * 2];
        tile[r][tx * 2]     = (short)(vv & 0xffff);
        tile[r][tx * 2 + 1] = (short)(((unsigned)vv) >> 16);
    }
    __syncthreads();
    #pragma unroll
    for (int i = 0; i < 8; ++i) {
        int G = i * 256 + threadIdx.x;     // 0..2047
        int ch2 = G >> 10;
        int rem = G & 1023;
        int dl = rem >> 4;
        int mp = rem & 15;
        int dval = c0 + dl;
        int h = dval >> 7, d128 = dval & 127;
        int g  = (mp >> 2) ^ (d128 & 3);
        int mi = mp & 3;
        int kl = 4 * g + 2 * (mi & 1) + 16 * (mi >> 1);
        unsigned lo = (unsigned short)tile[ch2 * 32 + kl][dl];
        unsigned hi = (unsigned short)tile[ch2 * 32 + kl + 1][dl];
        int chg = (t0 >> 5) + ch2;
        size_t off = ((size_t)(h * 64 + chg)) * 4096 + d128 * 32 + mp * 2;
        *(int*)&vTc[off] = (int)(lo | (hi << 16));
    }
}

// ---------------------------------------------------------------------------
// MFMA bf16 GEMM (128x128 tile, BK=64), proven structure — down-proj only.
// ---------------------------------------------------------------------------
__global__ __launch_bounds__(256) void gemm_bt(const short* __restrict__ A,
                                               const short* __restrict__ A2,
                                               const short* __restrict__ Bt,
                                               short* __restrict__ C0,
                                               short* __restrict__ C1,
                                               short* __restrict__ C2,
                                               short* __restrict__ C3,
                                               int N, int Kblk,
                                               int lda, int ldb, int ldc,
                                               int ncut, int scut, float cscale) {
    __shared__ short As[128 * 64];
    __shared__ short Bs[128 * 64];
    const int tid = threadIdx.x;
    const int wave = tid >> 6, lane = tid & 63;
    const int lin = blockIdx.x;
    const int X = N >> 7, Xq = X >> 2;
    const int xcd = lin & 7;
    int r = lin >> 3;
    const int bx = (xcd & 3) * Xq + (r % Xq); r /= Xq;
    const int by = (xcd >> 2) * 8 + (r & 7);
    const int bz = r >> 3;
    const int row0 = by * 128, col0 = bx * 128;
    const int kbase = bz * Kblk;
    const short* Ause = (col0 < ncut) ? A : A2;
    short* Cuse = (bz == 0) ? C0 : (bz == 1) ? C1 : (bz == 2) ? C2 : C3;
    const int wr = (wave >> 1) * 64, wc = (wave & 1) * 64;
    const int lr = lane & 15, quad = lane >> 4;

    f32x4 acc[4][4];
    #pragma unroll
    for (int i = 0; i < 4; ++i)
        #pragma unroll
        for (int j = 0; j < 4; ++j) acc[i][j] = (f32x4){0.f, 0.f, 0.f, 0.f};

    for (int k0 = kbase; k0 < kbase + Kblk; k0 += 64) {
        __syncthreads();
        #pragma unroll
        for (int it = 0; it < 4; ++it) {
            int idx = wave * 64 + it * 256 + lane;      // 0..1023
            int row = idx >> 3;
            int scg = (idx & 7) ^ (row & 7);
            const short* ga = Ause + (size_t)(row0 + row) * lda + k0 + scg * 8;
            const short* gb = Bt   + (size_t)(col0 + row) * ldb + k0 + scg * 8;
            int lds0 = (wave * 64 + it * 256) * 8;
            GLD_LDS(ga, &As[lds0]);
            GLD_LDS(gb, &Bs[lds0]);
        }
        __syncthreads();

        #pragma unroll
        for (int kk = 0; kk < 2; ++kk) {
            short8 af[4], bfr[4];
            #pragma unroll
            for (int i = 0; i < 4; ++i)
                af[i] = *(const short8*)
                    &As[(wr + i * 16 + lr) * 64 + (((kk * 4 + quad) ^ (lr & 7)) * 8)];
            #pragma unroll
            for (int j = 0; j < 4; ++j)
                bfr[j] = *(const short8*)
                    &Bs[(wc + j * 16 + lr) * 64 + (((kk * 4 + quad) ^ (lr & 7)) * 8)];
            #pragma unroll
            for (int i = 0; i < 4; ++i)
                #pragma unroll
                for (int j = 0; j < 4; ++j)
                    acc[i][j] = __builtin_amdgcn_mfma_f32_16x16x32_bf16(
                        af[i], bfr[j], acc[i][j], 0, 0, 0);
        }
    }

    const float sc = (col0 < scut) ? cscale : 1.0f;
    #pragma unroll
    for (int i = 0; i < 4; ++i) {
        int rb = row0 + wr + i * 16 + quad * 4;
        #pragma unroll
        for (int j = 0; j < 4; ++j) {
            int c = col0 + wc + j * 16 + lr;
            #pragma unroll
            for (int rr = 0; rr < 4; ++rr)
                Cuse[(size_t)(rb + rr) * ldc + c] = f2bf(acc[i][j][rr] * sc);
        }
    }
}

// ---------------------------------------------------------------------------
// DEEP-PIPELINED GEMM (this round): 256x128 tile, BK=64, 512 threads (8
// waves: wm=wave>>1 owns 64 A-rows, wn=wave&1 owns 64 B-cols), 3 LDS buffers
// (144KB, 1 block/CU), COUNTED-VMCNT schedule (T3/T4): 2 K-tiles (12 loads)
// always in flight; per K-tile one vmcnt(12) retiring exactly the tile about
// to be consumed + 2 raw s_barriers. Race-free by construction:
//   - stage of tile t+3 into buf t%3 issues only AFTER iteration t's end
//     barrier (all waves done reading buf t%3); next read of that buf is at
//     iteration t+3 AFTER a counted wait that drains those loads + barrier.
//   - asm memory clobbers pin LDS reads after the wait and stages after the
//     barrier (compiler cannot move loads across asm w/ "memory").
// LDS addressing = gemm_bt's PROVEN XOR scheme (0 conflicts measured).
// A-select (col0<ncut ? A:A2) + scale cols<scut; split via bz -> C0/C1.
// Grid decode: by = lin&7 (XCD-pinned A-row-panel -> same-XCD L2 reuse),
// bx = (lin>>3)%nbx, bz = (lin>>3)/nbx.
// ---------------------------------------------------------------------------
__device__ __forceinline__ void stage_tile256(const short* __restrict__ Ause,
                                              const short* __restrict__ Bt,
                                              int row0, int col0, int k0,
                                              int lda, int ldb,
                                              short* As, short* Bs, int tid) {
    #pragma unroll
    for (int it = 0; it < 4; ++it) {                 // A: 256x64 = 4 gld/thread
        int idx = it * 512 + tid;                    // 0..2047
        int row = idx >> 3;
        int scg = (idx & 7) ^ (row & 7);
        GLD_LDS(Ause + (size_t)(row0 + row) * lda + k0 + scg * 8, &As[idx * 8]);
    }
    #pragma unroll
    for (int it = 0; it < 2; ++it) {                 // B: 128x64 = 2 gld/thread
        int idx = it * 512 + tid;                    // 0..1023
        int row = idx >> 3;
        int scg = (idx & 7) ^ (row & 7);
        GLD_LDS(Bt + (size_t)(col0 + row) * ldb + k0 + scg * 8, &Bs[idx * 8]);
    }
}

__global__ __launch_bounds__(512) void gemm256_bt(const short* __restrict__ A,
                                                  const short* __restrict__ A2,
                                                  const short* __restrict__ Bt,
                                                  short* __restrict__ C0,
                                                  short* __restrict__ C1,
                                                  int nbx, int Kblk,
                                                  int lda, int ldb, int ldc,
                                                  int ncut, int scut, float cscale) {
    __shared__ short As3[3][256 * 64];   // 96KB
    __shared__ short Bs3[3][128 * 64];   // 48KB
    const int tid = threadIdx.x;
    const int wave = tid >> 6, lane = tid & 63;
    const int lr = lane & 15, quad = lane >> 4;
    const int wm = wave >> 1, wn = wave & 1;

    const int lin = blockIdx.x;
    const int by = lin & 7;
    const int rem = lin >> 3;
    const int bx = rem % nbx;
    const int bz = rem / nbx;
    const int row0 = by * 256, col0 = bx * 128;
    const int kbase = bz * Kblk;
    const short* Ause = (col0 < ncut) ? A : A2;
    short* Cuse = (bz == 0) ? C0 : C1;
    const int NT = Kblk >> 6;

    f32x4 acc[4][4];
    #pragma unroll
    for (int i = 0; i < 4; ++i)
        #pragma unroll
        for (int j = 0; j < 4; ++j) acc[i][j] = (f32x4){0.f, 0.f, 0.f, 0.f};

    // prologue: stage tiles 0,1,2 into bufs 0,1,2 (18 loads/wave in flight)
    #pragma unroll
    for (int tt = 0; tt < 3; ++tt)
        stage_tile256(Ause, Bt, row0, col0, kbase + tt * 64, lda, ldb,
                      &As3[tt][0], &Bs3[tt][0], tid);

    int b = 0;
    for (int t = 0; t < NT; ++t) {
        const int ahead = NT - 1 - t;
        // counted wait: retire exactly tile t's 6 loads; keep t+1,t+2 in flight
        if (ahead >= 2)      asm volatile("s_waitcnt vmcnt(12)" ::: "memory");
        else if (ahead == 1) asm volatile("s_waitcnt vmcnt(6)"  ::: "memory");
        else                 asm volatile("s_waitcnt vmcnt(0)"  ::: "memory");
        __builtin_amdgcn_s_barrier();                 // buf b complete for all
        asm volatile("" ::: "memory");

        const short* Ab = &As3[b][0];
        const short* Bb = &Bs3[b][0];
        short8 af[4][2], bfv[4][2];
        #pragma unroll
        for (int fi = 0; fi < 4; ++fi) {
            int rowa = wm * 64 + fi * 16 + lr;
            #pragma unroll
            for (int kk = 0; kk < 2; ++kk)
                af[fi][kk] = *(const short8*)
                    &Ab[rowa * 64 + (((kk * 4 + quad) ^ (lr & 7)) * 8)];
        }
        #pragma unroll
        for (int fj = 0; fj < 4; ++fj) {
            int rowb = wn * 64 + fj * 16 + lr;
            #pragma unroll
            for (int kk = 0; kk < 2; ++kk)
                bfv[fj][kk] = *(const short8*)
                    &Bb[rowb * 64 + (((kk * 4 + quad) ^ (lr & 7)) * 8)];
        }
        #pragma unroll
        for (int fi = 0; fi < 4; ++fi)
            #pragma unroll
            for (int fj = 0; fj < 4; ++fj)
                #pragma unroll
                for (int kk = 0; kk < 2; ++kk)
                    acc[fi][fj] = __builtin_amdgcn_mfma_f32_16x16x32_bf16(
                        af[fi][kk], bfv[fj][kk], acc[fi][fj], 0, 0, 0);

        asm volatile("" ::: "memory");
        __builtin_amdgcn_s_barrier();                 // all waves done with buf b
        asm volatile("" ::: "memory");
        if (t + 3 < NT)                               // refill freed buffer
            stage_tile256(Ause, Bt, row0, col0, kbase + (t + 3) * 64, lda, ldb,
                          &As3[b][0], &Bs3[b][0], tid);
        b = (b == 2) ? 0 : b + 1;
    }

    const float sc = (col0 < scut) ? cscale : 1.0f;
    #pragma unroll
    for (int fi = 0; fi < 4; ++fi) {
        int rb = row0 + wm * 64 + fi * 16 + quad * 4;
        #pragma unroll
        for (int fj = 0; fj < 4; ++fj) {
            int c = col0 + wn * 64 + fj * 16 + lr;
            #pragma unroll
            for (int rr = 0; rr < 4; ++rr)
                Cuse[(size_t)(rb + rr) * ldc + c] = f2bf(acc[fi][fj][rr] * sc);
        }
    }
}

// ---------------------------------------------------------------------------
// finish_down: cat += pdown (everywhere) then RoPE on cols 1024..3071.
// ---------------------------------------------------------------------------
__global__ __launch_bounds__(192) void finish_down(short* __restrict__ cat,
                                                   const short* __restrict__ pdown) {
    const int t = blockIdx.x;
    const int k8 = threadIdx.x * 8;                     // 0..1528
    const int c0 = ((k8 >> 5) << 6) + (k8 & 31);        // low-half col
    const size_t lo = (size_t)t * 3072 + c0;
    const size_t hi = lo + 32;
    short8 al = *(const short8*)&cat[lo];
    short8 ah = *(const short8*)&cat[hi];
    short8 bl = *(const short8*)&pdown[lo];
    short8 bh = *(const short8*)&pdown[hi];
    float xl[8], xh[8];
    #pragma unroll
    for (int j = 0; j < 8; ++j) {
        xl[j] = bf2f(al[j]) + bf2f(bl[j]);
        xh[j] = bf2f(ah[j]) + bf2f(bh[j]);
    }
    if (c0 >= 1024) {   // rope region
        float sc = (c0 < 2048) ? QSCALE : 1.0f;
        #pragma unroll
        for (int j = 0; j < 8; ++j) {
            int i = (c0 & 31) + j;
            float freq = (float)t * __powf(10000.0f, -(float)i / 32.0f);
            float cs = __cosf(freq), sn = __sinf(freq);
            float r1 = (xl[j] * cs - xh[j] * sn) * sc;
            float r2 = (xl[j] * sn + xh[j] * cs) * sc;
            xl[j] = r1; xh[j] = r2;
        }
    }
    short8 ol, oh;
    #pragma unroll
    for (int j = 0; j < 8; ++j) { ol[j] = f2bf(xl[j]); oh[j] = f2bf(xh[j]); }
    *(short8*)&cat[lo] = ol;
    *(short8*)&cat[hi] = oh;
}

// ---------------------------------------------------------------------------
// out = p0+p1 (bf16 partials -> fp32), 4 elems/thread
// ---------------------------------------------------------------------------
__global__ __launch_bounds__(256) void add_out_f32(const short* __restrict__ p0,
                                                   const short* __restrict__ p1,
                                                   float* __restrict__ out) {
    int i = (blockIdx.x * 256 + threadIdx.x) * 4;
    short4v a = *(const short4v*)&p0[i];
    short4v b = *(const short4v*)&p1[i];
    float4 o;
    o.x = bf2f(a.x) + bf2f(b.x);
    o.y = bf2f(a.y) + bf2f(b.y);
    o.z = bf2f(a.z) + bf2f(b.z);
    o.w = bf2f(a.w) + bf2f(b.w);
    *(float4*)&out[i] = o;
}

// ---------------------------------------------------------------------------
// Flash-decoding MFMA attention — r9-exact (swapped QK^T + in-register P;
// setprio removed: r11 A/B showed it negative on this barrier-locked kernel).
// ---------------------------------------------------------------------------
__global__ __launch_bounds__(256) void attn_mla_split(const short* __restrict__ qkup,
                                                      const short* __restrict__ cat,
                                                      const short* __restrict__ vTc,
                                                      short* __restrict__ slabA,
                                                      short* __restrict__ slabB,
                                                      float* __restrict__ lpart) {
    const int lin = blockIdx.x;        // 0..735
    const int xcd = lin & 7;
    int k_ = lin >> 3;                 // 0..91
    const int h = xcd + 8 * (k_ & 1);
    const int pp = k_ >> 1;            // 0..45: per-head segment index
    int qt = 0, s = 0, acc = 0;
    #pragma unroll
    for (int q = 0; q < 16; ++q) {
        const int ns = NSEG_OF(q);
        if (pp >= acc) { qt = q; s = pp - acc; }
        acc += ns;
    }
    const int nchunk = 2 * qt + 2;
    const int nsq = NSEG_OF(qt);
    const int cbase = nchunk / nsq, crem = nchunk % nsq;
    const int c0 = s * cbase + (s < crem ? s : crem);
    const int c1 = c0 + cbase + (s < crem ? 1 : 0);

    const int tid = threadIdx.x;
    const int wave = tid >> 6, lane = tid & 63;
    const int lr = lane & 15, quad = lane >> 4;

    __shared__ short Ks[2][32 * 128];
    __shared__ short Vst[2][128 * 32];

    const short8 ones = {0x3F80, 0x3F80, 0x3F80, 0x3F80,
                         0x3F80, 0x3F80, 0x3F80, 0x3F80};

    const int Q0 = qt * 128;
    const int qrowA = Q0 + wave * 16;
    const int qrowB = qrowA + 64;

    short8 qf[2][4];
    #pragma unroll
    for (int sb = 0; sb < 2; ++sb) {
        int t = (sb ? qrowB : qrowA) + lr;
        #pragma unroll
        for (int kci = 0; kci < 4; ++kci) {
            const short* src = (kci < 2)
                ? qkup + (size_t)t * 4096 + h * 64
                : cat + (size_t)t * 3072 + 1024 + h * 64;
            qf[sb][kci] = *(const short8*)&src[(kci & 1) * 32 + quad * 8];
        }
    }

    const int idx = wave * 64 + lane;
    const int key = idx >> 4;
    const int cg = (idx & 15) ^ (key & 15);
    const short* kp0 = (cg < 8)
        ? qkup + (size_t)key * 4096 + 1024 + h * 64 + cg * 8
        : cat + (size_t)key * 3072 + 2048 + h * 64 + (cg - 8) * 8;
    const int kst = (cg < 8) ? 4096 : 3072;
    const short* kp1 = kp0 + (size_t)16 * kst;
    const short* vp0 = vTc + ((size_t)h * 64 + (size_t)c0 * 2) * 4096 + idx * 8;
    kp0 += (size_t)c0 * 64 * kst; kp1 += (size_t)c0 * 64 * kst;
    const int kadv = 64 * kst;
    const int kph = 32 * kst;
    const int ldsA = (wave * 64) * 8;
    const int ldsB = (wave * 64 + 256) * 8;

    f32x4 Oacc[2][8];
    #pragma unroll
    for (int sb = 0; sb < 2; ++sb)
        #pragma unroll
        for (int d = 0; d < 8; ++d) Oacc[sb][d] = (f32x4){0.f, 0.f, 0.f, 0.f};
    f32x4 Lacc[2];
    Lacc[0] = (f32x4){0.f, 0.f, 0.f, 0.f};
    Lacc[1] = (f32x4){0.f, 0.f, 0.f, 0.f};

    for (int cc = c0; cc < c1; ++cc) {
        __syncthreads();
        GLD_LDS(kp0,        &Ks[0][ldsA]);
        GLD_LDS(kp1,        &Ks[0][ldsB]);
        GLD_LDS(kp0 + kph,  &Ks[1][ldsA]);
        GLD_LDS(kp1 + kph,  &Ks[1][ldsB]);
        GLD_LDS(vp0,        &Vst[0][ldsA]);
        GLD_LDS(vp0 + 2048, &Vst[0][ldsB]);
        GLD_LDS(vp0 + 4096, &Vst[1][ldsA]);
        GLD_LDS(vp0 + 6144, &Vst[1][ldsB]);
        kp0 += kadv; kp1 += kadv; vp0 += 8192;
        __syncthreads();

        #pragma unroll
        for (int half = 0; half < 2; ++half) {
            const int s0 = cc * 64 + half * 32;
            if (s0 > qrowB + 15) continue;
            const bool actA = (s0 <= qrowA + 15);
            const short* Kc = Ks[half];
            const short* Vc = Vst[half];

            f32x4 sacc[2][2];
            #pragma unroll
            for (int sb = 0; sb < 2; ++sb)
                #pragma unroll
                for (int n = 0; n < 2; ++n) sacc[sb][n] = (f32x4){0.f, 0.f, 0.f, 0.f};
            #pragma unroll
            for (int n = 0; n < 2; ++n) {
                #pragma unroll
                for (int kci = 0; kci < 4; ++kci) {
                    short8 kf = *(const short8*)
                        &Kc[(n * 16 + lr) * 128 + ((kci * 4 + quad) ^ lr) * 8];
                    if (actA)
                        sacc[0][n] = __builtin_amdgcn_mfma_f32_16x16x32_bf16(
                            kf, qf[0][kci], sacc[0][n], 0, 0, 0);
                    sacc[1][n] = __builtin_amdgcn_mfma_f32_16x16x32_bf16(
                        kf, qf[1][kci], sacc[1][n], 0, 0, 0);
                }
            }
            short8 paA, paB;
            #pragma unroll
            for (int sb = 0; sb < 2; ++sb) {
                if (sb == 0 && !actA) continue;
                const int qrow0 = sb ? qrowB : qrowA;
                if (s0 + 31 > qrow0) {
                    #pragma unroll
                    for (int n = 0; n < 2; ++n) {
                        #pragma unroll
                        for (int r = 0; r < 4; ++r) {
                            int kidx = s0 + n * 16 + quad * 4 + r;
                            sacc[sb][n][r] = (kidx <= qrow0 + lr)
                                           ? sacc[sb][n][r] : -1e30f;
                        }
                    }
                }
                int4 pw;
                pw.x = (int)(f2bf_tru(EXP2(sacc[sb][0][0])) |
                             (f2bf_tru(EXP2(sacc[sb][0][1])) << 16));
                pw.y = (int)(f2bf_tru(EXP2(sacc[sb][0][2])) |
                             (f2bf_tru(EXP2(sacc[sb][0][3])) << 16));
                pw.z = (int)(f2bf_tru(EXP2(sacc[sb][1][0])) |
                             (f2bf_tru(EXP2(sacc[sb][1][1])) << 16));
                pw.w = (int)(f2bf_tru(EXP2(sacc[sb][1][2])) |
                             (f2bf_tru(EXP2(sacc[sb][1][3])) << 16));
                if (sb) paB = __builtin_bit_cast(short8, pw);
                else    paA = __builtin_bit_cast(short8, pw);
            }
            if (actA)
                Lacc[0] = __builtin_amdgcn_mfma_f32_16x16x32_bf16(paA, ones,
                                                                  Lacc[0], 0, 0, 0);
            Lacc[1] = __builtin_amdgcn_mfma_f32_16x16x32_bf16(paB, ones,
                                                              Lacc[1], 0, 0, 0);
            #pragma unroll
            for (int dt = 0; dt < 8; ++dt) {
                short8 vf = *(const short8*)
                    &Vc[(dt * 16 + lr) * 32 + (quad ^ (lr & 3)) * 8];
                if (actA)
                    Oacc[0][dt] = __builtin_amdgcn_mfma_f32_16x16x32_bf16(
                        paA, vf, Oacc[0][dt], 0, 0, 0);
                Oacc[1][dt] = __builtin_amdgcn_mfma_f32_16x16x32_bf16(
                    paB, vf, Oacc[1][dt], 0, 0, 0);
            }
        }
    }

    const int slot = h * NSEG_TOT + pp;
    short* slotp = (slot < 512) ? slabA + (size_t)slot * 16384
                                : slabB + (size_t)(slot - 512) * 16384;
    #pragma unroll
    for (int sb = 0; sb < 2; ++sb) {
        const int rbase = wave * 16 + sb * 64 + quad * 4;
        #pragma unroll
        for (int r = 0; r < 4; ++r) {
            #pragma unroll
            for (int dt = 0; dt < 8; ++dt)
                slotp[(rbase + r) * 128 + dt * 16 + lr] = f2bf(Oacc[sb][dt][r]);
        }
        if (lr == 0) {
            #pragma unroll
            for (int r = 0; r < 4; ++r)
                lpart[(size_t)slot * 128 + rbase + r] = Lacc[sb][r];
        }
    }
}

// ---------------------------------------------------------------------------
// Combine: O[t, h*128+d] = (sum_s P_s) / (sum_s l_s), nseg(qt) partials.
// ---------------------------------------------------------------------------
__global__ __launch_bounds__(256) void attn_combine(const short* __restrict__ slabA,
                                                    const short* __restrict__ slabB,
                                                    const float* __restrict__ lpart,
                                                    short* __restrict__ ao) {
    const int t = blockIdx.x;
    const int qt = t >> 7, rl = t & 127;
    const int h = threadIdx.x >> 4;
    const int di = (threadIdx.x & 15) * 8;
    int pf = 0;
    #pragma unroll
    for (int q = 0; q < 16; ++q)
        if (q < qt) pf += NSEG_OF(q);
    const int ns = NSEG_OF(qt);
    float o[8] = {0.f, 0.f, 0.f, 0.f, 0.f, 0.f, 0.f, 0.f};
    float den = 0.f;
    for (int s = 0; s < ns; ++s) {
        const int slot = h * NSEG_TOT + pf + s;
        const short* sp = (slot < 512) ? slabA + (size_t)slot * 16384
                                       : slabB + (size_t)(slot - 512) * 16384;
        short8 v = *(const short8*)&sp[rl * 128 + di];
        #pragma unroll
        for (int j = 0; j < 8; ++j) o[j] += bf2f(v[j]);
        den += lpart[(size_t)slot * 128 + rl];
    }
    float inv = 1.0f / den;
    short8 ov;
    #pragma unroll
    for (int j = 0; j < 8; ++j) ov[j] = f2bf(o[j] * inv);
    *(short8*)&ao[(size_t)t * 2048 + h * 128 + di] = ov;
}

// ---------------------------------------------------------------------------
// Launch
// ---------------------------------------------------------------------------
extern "C" void kernel_launch(void* const* d_in, const int* in_sizes, int n_in,
                              void* d_out, int out_size, void* d_ws, size_t ws_size,
                              hipStream_t stream) {
    const float* x        = (const float*)d_in[0];
    const float* Wq_down  = (const float*)d_in[1];
    const float* Wq_up    = (const float*)d_in[2];
    const float* Wq_rope  = (const float*)d_in[3];
    const float* Wkv_down = (const float*)d_in[4];
    const float* Wk_up    = (const float*)d_in[5];
    const float* Wv_up    = (const float*)d_in[6];
    const float* Wk_rope  = (const float*)d_in[7];
    const float* Wo       = (const float*)d_in[8];
    float* out = (float*)d_out;

    short* p = (short*)d_ws;
    short* xb     = p; p += (size_t)2048 * 2048;   // 8MB
    short* WoT    = p; p += (size_t)2048 * 2048;   // 8MB
    short* cat    = p; p += (size_t)2048 * 3072;   // 12MB [qlat|kvlat|qr|kr]
    short* upcat2 = p; p += (size_t)2048 * 4096;   // 16MB [qc|kc|v]
    short* WdT    = p; p += (size_t)3072 * 2048;   // 12MB
    short* WupT2  = p; p += (size_t)4096 * 512;    // 4MB
    short* vTc    = p; p += (size_t)2048 * 2048;   // 8MB (chunk-blocked V)
    float* lpart  = (float*)p;                     // 736*128 floats (~377KB)
    short* pdown   = upcat2;
    short* aob     = cat;
    short* slabA   = WdT;          // WdT+WupT2 contiguous = 16MB = 512 slots
    short* slabB   = xb;           // 8MB = 256 slots (224 used)
    short* pw0     = upcat2;
    short* pw1     = upcat2 + (size_t)2048 * 2048;

    // prep: cast x + all weight transposes (one launch)
    prep<<<dim3(16384), 256, 0, stream>>>(x, xb, Wq_down, Wkv_down, Wq_rope,
                                          Wk_rope, Wq_up, Wk_up, Wv_up, Wo,
                                          WdT, WupT2, WoT);

    // down+rope projection, K split in 2: cat (z=0) + pdown (z=1)
    gemm_bt<<<dim3(24 * 16 * 2), 256, 0, stream>>>(xb, xb, WdT, cat, pdown,
                                                   nullptr, nullptr,
                                                   3072, 1024,
                                                   2048, 2048, 3072, 1 << 30, 0, 1.f);

    // fused: cat += pdown, then RoPE on qr/kr (qr scaled by QSCALE)
    finish_down<<<dim3(2048), 192, 0, stream>>>(cat, pdown);

    // merged up projection (deep-pipelined 256x128): 8 by x 32 bx = 256
    // blocks, 1/CU exact. qc cols (<1024) pre-scaled by QSCALE.
    gemm256_bt<<<dim3(256), 512, 0, stream>>>(cat, cat + 512, WupT2,
                                              upcat2, nullptr,
                                              32, 512,
                                              3072, 512, 4096, 1024, 1024, QSCALE);

    // v transpose: upcat2 cols 2048..4095 -> chunk-blocked vTc
    transpose_bf16<<<dim3(32, 32), 256, 0, stream>>>(upcat2 + 2048, vTc, 4096);

    // attention partials (64-key rounds, balanced variable split) + combine
    attn_mla_split<<<dim3(16 * NSEG_TOT), 256, 0, stream>>>(upcat2, cat, vTc,
                                                            slabA, slabB, lpart);
    attn_combine<<<dim3(2048), 256, 0, stream>>>(slabA, slabB, lpart, aob);

    // output projection (deep-pipelined 256x128), K split in 2:
    // 8 by x 16 bx x 2 bz = 256 blocks, 1/CU exact; then fp32 add
    gemm256_bt<<<dim3(256), 512, 0, stream>>>(aob, aob, WoT,
                                              pw0, pw1,
                                              16, 1024,
                                              2048, 2048, 2048, 1 << 30, 0, 1.f);
    add_out_f32<<<dim3(2048 * 2048 / 1024), 256, 0, stream>>>(pw0, pw1, out);
}